// Round 7
// baseline (49.919 us; speedup 1.0000x reference)
//
#include <hip/hip_runtime.h>

#define G_ 19
#define A_ 5
#define C_ 20
#define BS_ 16
#define N_ (G_*G_*A_)        // 1805
#define CHK 8                // segments (blocks) per batch
#define SEG 256              // slots per segment
#define NBLK (BS_*CHK)       // 128
#define PMAX 1808            // packed pos capacity (>= N_)
#define EPSF 1e-8f

// ws byte offsets (16B-aligned blocks)
#define OFF_P1  0                               // float[128]  loss partials
#define OFF_CP  (OFF_P1 + NBLK*4)               // u32[128]
#define OFF_CN  (OFF_CP + NBLK*4)               // u32[128]
#define OFF_PLB (OFF_CN + NBLK*4 + 4)           // pad to 16 -> float4[128*256]
#define OFF_PLA (OFF_PLB + NBLK*SEG*16)         // float[128*256]
#define OFF_NLB (OFF_PLA + NBLK*SEG*4)          // float4[128*256]
#define OFF_NLV (OFF_NLB + NBLK*SEG*16)         // float[128*256]

__device__ __forceinline__ float sigmoidf_(float x) {
    return 1.0f / (1.0f + __expf(-x));
}

__global__ __launch_bounds__(256) void k1_elemwise(
    const float* __restrict__ pred, const float* __restrict__ gt,
    const float* __restrict__ anch, const int* __restrict__ epoch_p,
    char* __restrict__ ws, float* __restrict__ out)
{
    float*    partial1 = (float*)(ws + OFF_P1);
    unsigned* cntP  = (unsigned*)(ws + OFF_CP);
    unsigned* cntN  = (unsigned*)(ws + OFF_CN);
    float4*   plbox = (float4*)(ws + OFF_PLB);
    float*    plab  = (float*) (ws + OFF_PLA);
    float4*   nlbox = (float4*)(ws + OFF_NLB);
    float*    nlval = (float*) (ws + OFF_NLV);

    __shared__ __align__(16) float sp[256*25];   // 25.6 KB
    __shared__ __align__(16) float sg[256*25];   // 25.6 KB
    __shared__ float red[4];
    __shared__ int wpo[4], wno[4];

    const int tid  = threadIdx.x;
    const int lane = tid & 63, wid = tid >> 6;
    const int b    = blockIdx.y;
    const int ch   = blockIdx.x;
    const int blin = b * CHK + ch;

    if (blin == 0 && tid == 0) out[0] = 0.f;     // safe: k2's atomics are in a later dispatch

    int n0   = ch * 256;
    int rows = min(256, N_ - n0);
    int ndw  = rows * 25;
    const float* srcP = pred + ((size_t)b*N_ + n0)*25;
    const float* srcG = gt   + ((size_t)b*N_ + n0)*25;
    for (int d = tid; d < ndw; d += 256) { sp[d] = srcP[d]; sg[d] = srcG[d]; }
    __syncthreads();

    int n = n0 + tid;
    bool valid = tid < rows;
    const float* P = sp + tid*25;
    const float* T = sg + tid*25;
    float local = 0.f;

    bool pos = false;
    float gx1=0, gy1=0, gx2=0, gy2=0, area_g=0;
    float px1=0, py1=0, px2=0, py2=0, pconf=0;

    if (valid) {
        int a  = n % A_;
        int g2 = (n / A_) % G_;
        int g1 = n / (A_ * G_);
        float px = P[0], py = P[1], pw = P[2], ph = P[3], po = P[4];
        float gx = T[0], gy = T[1], gw = T[2], gh = T[3], go = T[4];
        float aw = anch[a*2+0], ah = anch[a*2+1];

        float sx  = sigmoidf_(px), sy = sigmoidf_(py);
        float pbw = __expf(pw) * aw, pbh = __expf(ph) * ah;
        float gbw = __expf(gw) * aw, gbh = __expf(gh) * ah;

        float cxp = sx + (float)g2, cyp = sy + (float)g1;
        float hwp = pbw * (0.5f * G_), hhp = pbh * (0.5f * G_);
        px1 = cxp - hwp; py1 = cyp - hhp; px2 = cxp + hwp; py2 = cyp + hhp;

        float cxg = gx + (float)g2, cyg = gy + (float)g1;
        float hwg = gbw * (0.5f * G_), hhg = gbh * (0.5f * G_);
        gx1 = cxg - hwg; gy1 = cyg - hhg; gx2 = cxg + hwg; gy2 = cyg + hhg;

        pconf = sigmoidf_(po);
        float area_p = fmaxf(px2 - px1, 0.f) * fmaxf(py2 - py1, 0.f);
        area_g = fmaxf(gx2 - gx1, 0.f) * fmaxf(gy2 - gy1, 0.f);

        if (*epoch_p < 12) {
            local += 0.01f * (px*px + py*py + pw*pw + ph*ph);
        }
        pos = go > 0.5f;
        if (pos) {
            float d0 = gx - sx, d1 = gy - sy, d2 = gw - pw, d3 = gh - ph;
            local += 5.0f * (d0*d0 + d1*d1 + d2*d2 + d3*d3);
            float ix1 = fmaxf(px1, gx1), iy1 = fmaxf(py1, gy1);
            float ix2 = fminf(px2, gx2), iy2 = fminf(py2, gy2);
            float iw = fmaxf(ix2 - ix1, 0.f), ih = fmaxf(iy2 - iy1, 0.f);
            float inter = iw * ih;
            float iou = inter / (area_p + area_g - inter + EPSF);
            float dc = iou - pconf;
            local += dc * dc;
            float cl[C_];
            float m = -1e30f;
            #pragma unroll
            for (int c = 0; c < C_; c++) { cl[c] = P[5+c]; m = fmaxf(m, cl[c]); }
            float s = 0.f;
            #pragma unroll
            for (int c = 0; c < C_; c++) { cl[c] = __expf(cl[c] - m); s += cl[c]; }
            float inv = 1.0f / s;
            float acc = 0.f;
            #pragma unroll
            for (int c = 0; c < C_; c++) { float d = T[5+c] - cl[c]*inv; acc += d*d; }
            local += acc;
        }
        local *= (1.0f / BS_);
    }

    // deterministic block-local compaction into this block's segment
    bool isPos = valid && pos;
    bool isNeg = valid && !pos;
    unsigned long long mp = __ballot(isPos);
    unsigned long long mn = __ballot(isNeg);
    unsigned long long ltm = (1ull << lane) - 1ull;
    int ppre = __popcll(mp & ltm);
    int npre = __popcll(mn & ltm);
    if (lane == 0) { wpo[wid] = __popcll(mp); wno[wid] = __popcll(mn); }
    __syncthreads();
    int pexc = 0, nexc = 0, tp = 0, tn = 0;
    #pragma unroll
    for (int w = 0; w < 4; w++) {
        if (w < wid) { pexc += wpo[w]; nexc += wno[w]; }
        tp += wpo[w]; tn += wno[w];
    }
    if (isPos) {
        int k = blin*SEG + pexc + ppre;
        plbox[k] = make_float4(gx1, gy1, gx2, gy2);
        plab[k]  = area_g;
    } else if (isNeg) {
        int k = blin*SEG + nexc + npre;
        nlbox[k] = make_float4(px1, py1, px2, py2);
        nlval[k] = (0.5f / BS_) * pconf * pconf;
    }
    if (tid == 0) { cntP[blin] = (unsigned)tp; cntN[blin] = (unsigned)tn; }

    // block loss partial
    for (int off = 32; off; off >>= 1) local += __shfl_down(local, off);
    if (lane == 0) red[wid] = local;
    __syncthreads();
    if (tid == 0) partial1[blin] = red[0] + red[1] + red[2] + red[3];
}

// k2': per (batch, i-segment) block; ALL j in-block -> fused noobj reduction.
__global__ __launch_bounds__(1024) void k2_fused(char* __restrict__ ws,
                                                 float* __restrict__ out)
{
    const float*    partial1 = (const float*)(ws + OFF_P1);
    const unsigned* cntP  = (const unsigned*)(ws + OFF_CP);
    const unsigned* cntN  = (const unsigned*)(ws + OFF_CN);
    const float4*   plbox = (const float4*)(ws + OFF_PLB);
    const float*    plab  = (const float*) (ws + OFF_PLA);
    const float4*   nlbox = (const float4*)(ws + OFF_NLB);
    const float*    nlval = (const float*) (ws + OFF_NLV);

    const int tid  = threadIdx.x;
    const int jq   = tid >> 8;          // 0..3
    const int ii   = tid & 255;
    const int iseg = blockIdx.x;        // 0..7
    const int b    = blockIdx.y;
    const int blin = b*CHK + iseg;

    __shared__ __align__(16) float4 sboxp[PMAX];   // 28.9 KB packed pos boxes
    __shared__ float sa06[PMAX];                   // 7.2 KB  -0.6*area_b
    __shared__ float smdr[1024];                   // 4 KB
    __shared__ int   scnt[8], spref[9];
    __shared__ float red[16];

    if (tid < 8) scnt[tid] = (int)cntP[b*CHK + tid];
    __syncthreads();
    if (tid == 0) {
        int s = 0;
        #pragma unroll
        for (int w = 0; w < 8; w++) { spref[w] = s; s += scnt[w]; }
        spref[8] = s;
    }
    __syncthreads();
    const int npos = spref[8];

    // pack all pos boxes of batch b into contiguous LDS
    #pragma unroll
    for (int rep = 0; rep < 2; rep++) {
        int seg = rep*4 + jq;
        if (ii < scnt[seg]) {
            int src = (b*CHK + seg)*SEG + ii;
            int dst = spref[seg] + ii;
            sboxp[dst] = plbox[src];
            sa06[dst]  = -0.6f * plab[src];
        }
    }
    __syncthreads();

    const int nn = (int)cntN[blin];
    const bool valid = ii < nn;
    float4 p = nlbox[blin*SEG + ii];     // poison-safe for invalid ii (discarded)
    float c0 = (p.z - p.x) * (p.w - p.y) + EPSF;

    float md = -1e30f;
    for (int j = jq; j < npos; j += 4) {
        float4 g = sboxp[j];
        float tt = sa06[j];
        float ax = fmaxf(p.x, g.x), ay = fmaxf(p.y, g.y);
        float bx = fminf(p.z, g.z), by = fminf(p.w, g.w);
        float in0 = fmaxf(bx - ax, 0.f) * fmaxf(by - ay, 0.f);
        md = fmaxf(md, fmaf(1.6f, in0, tt));   // 1.6*inter - 0.6*area_b
    }
    smdr[tid] = md;
    __syncthreads();

    float v = 0.f;
    if (tid < 256) {
        float m0 = fmaxf(fmaxf(smdr[tid], smdr[tid+256]),
                         fmaxf(smdr[tid+512], smdr[tid+768]));
        // kept (noobj) <=> NOT (iou >= 0.6) <=> m0 < 0.6*(area_a+eps)
        if (valid && m0 < 0.6f * c0) v = nlval[blin*SEG + ii];
        if (tid == 0) v += partial1[blin];
    }
    for (int off = 32; off; off >>= 1) v += __shfl_down(v, off);
    int wid = tid >> 6, lane = tid & 63;
    if (lane == 0) red[wid] = v;
    __syncthreads();
    if (tid == 0) {
        float s = 0.f;
        #pragma unroll
        for (int w = 0; w < 16; w++) s += red[w];
        atomicAdd(out, s);
    }
}

extern "C" void kernel_launch(void* const* d_in, const int* in_sizes, int n_in,
                              void* d_out, int out_size, void* d_ws, size_t ws_size,
                              hipStream_t stream) {
    const float* pred  = (const float*)d_in[0];
    const float* gt_   = (const float*)d_in[1];
    const float* anch  = (const float*)d_in[2];
    const int*   epoch = (const int*)d_in[3];
    float* out = (float*)d_out;
    char*  ws  = (char*)d_ws;

    dim3 g1(CHK, BS_);
    k1_elemwise<<<g1, 256, 0, stream>>>(pred, gt_, anch, epoch, ws, out);
    dim3 g2(CHK, BS_);
    k2_fused<<<g2, 1024, 0, stream>>>(ws, out);
}

// Round 8
// 40.220 us; speedup vs baseline: 1.2411x; 1.2411x over previous
//
#include <hip/hip_runtime.h>

#define G_ 19
#define A_ 5
#define C_ 20
#define BS_ 16
#define N_ (G_*G_*A_)        // 1805
#define CHK 8                // segments (blocks) per batch
#define SEG 256              // slots per segment
#define NBLK (BS_*CHK)       // 128
#define EPSF 1e-8f

// ws byte offsets (16B-aligned blocks)
#define OFF_P1  0                               // float[128]  loss partials
#define OFF_CP  (OFF_P1 + NBLK*4)               // u32[128]
#define OFF_CN  (OFF_CP + NBLK*4)               // u32[128]
#define OFF_PLB (OFF_CN + NBLK*4 + 4)           // pad to 16 -> float4[128*256]
#define OFF_PLA (OFF_PLB + NBLK*SEG*16)         // float[128*256]  (-0.6*area_g)
#define OFF_NLB (OFF_PLA + NBLK*SEG*4)          // float4[128*256]
#define OFF_NLV (OFF_NLB + NBLK*SEG*16)         // float[128*256]

__device__ __forceinline__ float sigmoidf_(float x) {
    return 1.0f / (1.0f + __expf(-x));
}

__global__ __launch_bounds__(256) void k1_elemwise(
    const float* __restrict__ pred, const float* __restrict__ gt,
    const float* __restrict__ anch, const int* __restrict__ epoch_p,
    char* __restrict__ ws, float* __restrict__ out)
{
    float*    partial1 = (float*)(ws + OFF_P1);
    unsigned* cntP  = (unsigned*)(ws + OFF_CP);
    unsigned* cntN  = (unsigned*)(ws + OFF_CN);
    float4*   plbox = (float4*)(ws + OFF_PLB);
    float*    plab  = (float*) (ws + OFF_PLA);
    float4*   nlbox = (float4*)(ws + OFF_NLB);
    float*    nlval = (float*) (ws + OFF_NLV);

    __shared__ __align__(16) float sp[256*25];   // 25.6 KB
    __shared__ __align__(16) float sg[256*25];   // 25.6 KB
    __shared__ float red[4];
    __shared__ int wpo[4], wno[4];

    const int tid  = threadIdx.x;
    const int lane = tid & 63, wid = tid >> 6;
    const int b    = blockIdx.y;
    const int ch   = blockIdx.x;
    const int blin = b * CHK + ch;

    if (blin == 0 && tid == 0) out[0] = 0.f;     // safe: k2's atomics are in a later dispatch

    int n0   = ch * 256;
    int rows = min(256, N_ - n0);
    int ndw  = rows * 25;
    const float* srcP = pred + ((size_t)b*N_ + n0)*25;
    const float* srcG = gt   + ((size_t)b*N_ + n0)*25;
    for (int d = tid; d < ndw; d += 256) { sp[d] = srcP[d]; sg[d] = srcG[d]; }
    __syncthreads();

    int n = n0 + tid;
    bool valid = tid < rows;
    const float* P = sp + tid*25;
    const float* T = sg + tid*25;
    float local = 0.f;

    bool pos = false;
    float gx1=0, gy1=0, gx2=0, gy2=0, area_g=0;
    float px1=0, py1=0, px2=0, py2=0, pconf=0;

    if (valid) {
        int a  = n % A_;
        int g2 = (n / A_) % G_;
        int g1 = n / (A_ * G_);
        float px = P[0], py = P[1], pw = P[2], ph = P[3], po = P[4];
        float gx = T[0], gy = T[1], gw = T[2], gh = T[3], go = T[4];
        float aw = anch[a*2+0], ah = anch[a*2+1];

        float sx  = sigmoidf_(px), sy = sigmoidf_(py);
        float pbw = __expf(pw) * aw, pbh = __expf(ph) * ah;
        float gbw = __expf(gw) * aw, gbh = __expf(gh) * ah;

        float cxp = sx + (float)g2, cyp = sy + (float)g1;
        float hwp = pbw * (0.5f * G_), hhp = pbh * (0.5f * G_);
        px1 = cxp - hwp; py1 = cyp - hhp; px2 = cxp + hwp; py2 = cyp + hhp;

        float cxg = gx + (float)g2, cyg = gy + (float)g1;
        float hwg = gbw * (0.5f * G_), hhg = gbh * (0.5f * G_);
        gx1 = cxg - hwg; gy1 = cyg - hhg; gx2 = cxg + hwg; gy2 = cyg + hhg;

        pconf = sigmoidf_(po);
        float area_p = fmaxf(px2 - px1, 0.f) * fmaxf(py2 - py1, 0.f);
        area_g = fmaxf(gx2 - gx1, 0.f) * fmaxf(gy2 - gy1, 0.f);

        if (*epoch_p < 12) {
            local += 0.01f * (px*px + py*py + pw*pw + ph*ph);
        }
        pos = go > 0.5f;
        if (pos) {
            float d0 = gx - sx, d1 = gy - sy, d2 = gw - pw, d3 = gh - ph;
            local += 5.0f * (d0*d0 + d1*d1 + d2*d2 + d3*d3);
            float ix1 = fmaxf(px1, gx1), iy1 = fmaxf(py1, gy1);
            float ix2 = fminf(px2, gx2), iy2 = fminf(py2, gy2);
            float iw = fmaxf(ix2 - ix1, 0.f), ih = fmaxf(iy2 - iy1, 0.f);
            float inter = iw * ih;
            float iou = inter / (area_p + area_g - inter + EPSF);
            float dc = iou - pconf;
            local += dc * dc;
            float cl[C_];
            float m = -1e30f;
            #pragma unroll
            for (int c = 0; c < C_; c++) { cl[c] = P[5+c]; m = fmaxf(m, cl[c]); }
            float s = 0.f;
            #pragma unroll
            for (int c = 0; c < C_; c++) { cl[c] = __expf(cl[c] - m); s += cl[c]; }
            float inv = 1.0f / s;
            float acc = 0.f;
            #pragma unroll
            for (int c = 0; c < C_; c++) { float d = T[5+c] - cl[c]*inv; acc += d*d; }
            local += acc;
        }
        local *= (1.0f / BS_);
    }

    // deterministic block-local compaction into this block's segment
    bool isPos = valid && pos;
    bool isNeg = valid && !pos;
    unsigned long long mp = __ballot(isPos);
    unsigned long long mn = __ballot(isNeg);
    unsigned long long ltm = (1ull << lane) - 1ull;
    int ppre = __popcll(mp & ltm);
    int npre = __popcll(mn & ltm);
    if (lane == 0) { wpo[wid] = __popcll(mp); wno[wid] = __popcll(mn); }
    __syncthreads();
    int pexc = 0, nexc = 0, tp = 0, tn = 0;
    #pragma unroll
    for (int w = 0; w < 4; w++) {
        if (w < wid) { pexc += wpo[w]; nexc += wno[w]; }
        tp += wpo[w]; tn += wno[w];
    }
    if (isPos) {
        int k = blin*SEG + pexc + ppre;
        plbox[k] = make_float4(gx1, gy1, gx2, gy2);
        plab[k]  = -0.6f * area_g;                 // pre-scaled for k2's fma
    } else if (isNeg) {
        int k = blin*SEG + nexc + npre;
        nlbox[k] = make_float4(px1, py1, px2, py2);
        nlval[k] = (0.5f / BS_) * pconf * pconf;
    }
    if (tid == 0) { cntP[blin] = (unsigned)tp; cntN[blin] = (unsigned)tn; }

    // block loss partial
    for (int off = 32; off; off >>= 1) local += __shfl_down(local, off);
    if (lane == 0) red[wid] = local;
    __syncthreads();
    if (tid == 0) partial1[blin] = red[0] + red[1] + red[2] + red[3];
}

// k2: per (iseg, b, isub) block. j-boxes read with wave-uniform addresses
// (scalar-load path) -- no LDS staging. jq 4-way j-split; even/odd slot
// interleave across isub for balance.
__global__ __launch_bounds__(512) void k2_fused(char* __restrict__ ws,
                                                float* __restrict__ out)
{
    const float*    partial1 = (const float*)(ws + OFF_P1);
    const unsigned* cntP  = (const unsigned*)(ws + OFF_CP);
    const unsigned* cntN  = (const unsigned*)(ws + OFF_CN);
    const float4*   plbox = (const float4*)(ws + OFF_PLB);
    const float*    plab  = (const float*) (ws + OFF_PLA);
    const float4*   nlbox = (const float4*)(ws + OFF_NLB);
    const float*    nlval = (const float*) (ws + OFF_NLV);

    const int tid  = threadIdx.x;
    const int jq   = tid >> 7;          // 0..3 (uniform per wave)
    const int il   = tid & 127;
    const int iseg = blockIdx.x;        // 0..7
    const int b    = blockIdx.y;
    const int isub = blockIdx.z;        // 0..1
    const int blin = b*CHK + iseg;
    const int isl  = isub + 2*il;       // interleaved slot -> balanced halves

    __shared__ float smdr[512];
    __shared__ float red[8];

    const int nn = (int)cntN[blin];
    const bool valid = isl < nn;
    float4 p = nlbox[blin*SEG + isl];   // poison-safe if invalid (discarded)
    float t0 = 0.6f * ((p.z - p.x) * (p.w - p.y) + EPSF);

    float md = -1e30f;
    for (int seg = 0; seg < CHK; seg++) {
        const int cnt = (int)cntP[b*CHK + seg];        // uniform (SGPR)
        const float4* jb = plbox + (b*CHK + seg)*SEG;  // uniform base
        const float*  ja = plab  + (b*CHK + seg)*SEG;
        #pragma unroll 2
        for (int j = jq; j < cnt; j += 4) {            // uniform index per wave
            float4 g = jb[j];
            float a06 = ja[j];
            float ax = fmaxf(p.x, g.x), ay = fmaxf(p.y, g.y);
            float bx = fminf(p.z, g.z), by = fminf(p.w, g.w);
            float in0 = fmaxf(bx - ax, 0.f) * fmaxf(by - ay, 0.f);
            md = fmaxf(md, fmaf(1.6f, in0, a06));      // 1.6*inter - 0.6*area_b
        }
    }
    smdr[tid] = md;
    __syncthreads();

    float v = 0.f;
    if (tid < 128) {                    // these are the jq=0 threads (same il, same p/t0)
        float m0 = fmaxf(fmaxf(smdr[tid], smdr[tid+128]),
                         fmaxf(smdr[tid+256], smdr[tid+384]));
        // kept (noobj) <=> NOT (iou >= 0.6) <=> m0 < 0.6*(area_a+eps)
        if (valid && m0 < t0) v = nlval[blin*SEG + isl];
        if (tid == 0 && isub == 0) v += partial1[blin];
    }
    for (int off = 32; off; off >>= 1) v += __shfl_down(v, off);
    int wid = tid >> 6, lane = tid & 63;
    if (lane == 0) red[wid] = v;
    __syncthreads();
    if (tid == 0) {
        float s = 0.f;
        #pragma unroll
        for (int w = 0; w < 8; w++) s += red[w];
        atomicAdd(out, s);
    }
}

extern "C" void kernel_launch(void* const* d_in, const int* in_sizes, int n_in,
                              void* d_out, int out_size, void* d_ws, size_t ws_size,
                              hipStream_t stream) {
    const float* pred  = (const float*)d_in[0];
    const float* gt_   = (const float*)d_in[1];
    const float* anch  = (const float*)d_in[2];
    const int*   epoch = (const int*)d_in[3];
    float* out = (float*)d_out;
    char*  ws  = (char*)d_ws;

    dim3 g1(CHK, BS_);
    k1_elemwise<<<g1, 256, 0, stream>>>(pred, gt_, anch, epoch, ws, out);
    dim3 g2(CHK, BS_, 2);
    k2_fused<<<g2, 512, 0, stream>>>(ws, out);
}

// Round 9
// 32.897 us; speedup vs baseline: 1.5174x; 1.2226x over previous
//
#include <hip/hip_runtime.h>

#define G_ 19
#define A_ 5
#define C_ 20
#define BS_ 16
#define N_ (G_*G_*A_)        // 1805
#define CHK 8                // segments (blocks) per batch
#define SEG 256              // slots per segment
#define NBLK (BS_*CHK)       // 128
#define EPSF 1e-8f

// ws byte offsets (16B-aligned blocks)
#define OFF_P1  0                               // float[128]  loss partials
#define OFF_CP  (OFF_P1 + NBLK*4)               // u32[128]  (padded pos counts)
#define OFF_CN  (OFF_CP + NBLK*4)               // u32[128]
#define OFF_PLB (OFF_CN + NBLK*4 + 4)           // pad to 16 -> float4[128*256]
#define OFF_PLA (OFF_PLB + NBLK*SEG*16)         // float[128*256]  (-0.6*area_g)
#define OFF_NLB (OFF_PLA + NBLK*SEG*4)          // float4[128*256]
#define OFF_NLV (OFF_NLB + NBLK*SEG*16)         // float[128*256]

__device__ __forceinline__ float sigmoidf_(float x) {
    return 1.0f / (1.0f + __expf(-x));
}

__global__ __launch_bounds__(256) void k1_elemwise(
    const float* __restrict__ pred, const float* __restrict__ gt,
    const float* __restrict__ anch, const int* __restrict__ epoch_p,
    char* __restrict__ ws, float* __restrict__ out)
{
    float*    partial1 = (float*)(ws + OFF_P1);
    unsigned* cntP  = (unsigned*)(ws + OFF_CP);
    unsigned* cntN  = (unsigned*)(ws + OFF_CN);
    float4*   plbox = (float4*)(ws + OFF_PLB);
    float*    plab  = (float*) (ws + OFF_PLA);
    float4*   nlbox = (float4*)(ws + OFF_NLB);
    float*    nlval = (float*) (ws + OFF_NLV);

    __shared__ __align__(16) float sp[256*25];   // 25.6 KB
    __shared__ __align__(16) float sg[256*25];   // 25.6 KB
    __shared__ float red[4];
    __shared__ int wpo[4], wno[4];

    const int tid  = threadIdx.x;
    const int lane = tid & 63, wid = tid >> 6;
    const int b    = blockIdx.y;
    const int ch   = blockIdx.x;
    const int blin = b * CHK + ch;

    if (blin == 0 && tid == 0) out[0] = 0.f;     // safe: k2's atomics are in a later dispatch

    int n0   = ch * 256;
    int rows = min(256, N_ - n0);
    int ndw  = rows * 25;
    const float* srcP = pred + ((size_t)b*N_ + n0)*25;
    const float* srcG = gt   + ((size_t)b*N_ + n0)*25;
    for (int d = tid; d < ndw; d += 256) { sp[d] = srcP[d]; sg[d] = srcG[d]; }
    __syncthreads();

    int n = n0 + tid;
    bool valid = tid < rows;
    const float* P = sp + tid*25;
    const float* T = sg + tid*25;
    float local = 0.f;

    bool pos = false;
    float gx1=0, gy1=0, gx2=0, gy2=0, area_g=0;
    float px1=0, py1=0, px2=0, py2=0, pconf=0;

    if (valid) {
        int a  = n % A_;
        int g2 = (n / A_) % G_;
        int g1 = n / (A_ * G_);
        float px = P[0], py = P[1], pw = P[2], ph = P[3], po = P[4];
        float gx = T[0], gy = T[1], gw = T[2], gh = T[3], go = T[4];
        float aw = anch[a*2+0], ah = anch[a*2+1];

        float sx  = sigmoidf_(px), sy = sigmoidf_(py);
        float pbw = __expf(pw) * aw, pbh = __expf(ph) * ah;
        float gbw = __expf(gw) * aw, gbh = __expf(gh) * ah;

        float cxp = sx + (float)g2, cyp = sy + (float)g1;
        float hwp = pbw * (0.5f * G_), hhp = pbh * (0.5f * G_);
        px1 = cxp - hwp; py1 = cyp - hhp; px2 = cxp + hwp; py2 = cyp + hhp;

        float cxg = gx + (float)g2, cyg = gy + (float)g1;
        float hwg = gbw * (0.5f * G_), hhg = gbh * (0.5f * G_);
        gx1 = cxg - hwg; gy1 = cyg - hhg; gx2 = cxg + hwg; gy2 = cyg + hhg;

        pconf = sigmoidf_(po);
        float area_p = fmaxf(px2 - px1, 0.f) * fmaxf(py2 - py1, 0.f);
        area_g = fmaxf(gx2 - gx1, 0.f) * fmaxf(gy2 - gy1, 0.f);

        if (*epoch_p < 12) {
            local += 0.01f * (px*px + py*py + pw*pw + ph*ph);
        }
        pos = go > 0.5f;
        if (pos) {
            float d0 = gx - sx, d1 = gy - sy, d2 = gw - pw, d3 = gh - ph;
            local += 5.0f * (d0*d0 + d1*d1 + d2*d2 + d3*d3);
            float ix1 = fmaxf(px1, gx1), iy1 = fmaxf(py1, gy1);
            float ix2 = fminf(px2, gx2), iy2 = fminf(py2, gy2);
            float iw = fmaxf(ix2 - ix1, 0.f), ih = fmaxf(iy2 - iy1, 0.f);
            float inter = iw * ih;
            float iou = inter / (area_p + area_g - inter + EPSF);
            float dc = iou - pconf;
            local += dc * dc;
            float cl[C_];
            float m = -1e30f;
            #pragma unroll
            for (int c = 0; c < C_; c++) { cl[c] = P[5+c]; m = fmaxf(m, cl[c]); }
            float s = 0.f;
            #pragma unroll
            for (int c = 0; c < C_; c++) { cl[c] = __expf(cl[c] - m); s += cl[c]; }
            float inv = 1.0f / s;
            float acc = 0.f;
            #pragma unroll
            for (int c = 0; c < C_; c++) { float d = T[5+c] - cl[c]*inv; acc += d*d; }
            local += acc;
        }
        local *= (1.0f / BS_);
    }

    // deterministic block-local compaction into this block's segment
    bool isPos = valid && pos;
    bool isNeg = valid && !pos;
    unsigned long long mp = __ballot(isPos);
    unsigned long long mn = __ballot(isNeg);
    unsigned long long ltm = (1ull << lane) - 1ull;
    int ppre = __popcll(mp & ltm);
    int npre = __popcll(mn & ltm);
    if (lane == 0) { wpo[wid] = __popcll(mp); wno[wid] = __popcll(mn); }
    __syncthreads();
    int pexc = 0, nexc = 0, tp = 0, tn = 0;
    #pragma unroll
    for (int w = 0; w < 4; w++) {
        if (w < wid) { pexc += wpo[w]; nexc += wno[w]; }
        tp += wpo[w]; tn += wno[w];
    }
    if (isPos) {
        int k = blin*SEG + pexc + ppre;
        plbox[k] = make_float4(gx1, gy1, gx2, gy2);
        plab[k]  = -0.6f * area_g;                 // pre-scaled for k2's fma
    } else if (isNeg) {
        int k = blin*SEG + nexc + npre;
        nlbox[k] = make_float4(px1, py1, px2, py2);
        nlval[k] = (0.5f / BS_) * pconf * pconf;
    }
    // pad pos list to a multiple of 32 with inert dummies (inter=0, a06=-3e38)
    int padTo = (tp + 31) & ~31;                   // <= 256 always
    if (tid >= tp && tid < padTo) {
        plbox[blin*SEG + tid] = make_float4(3e8f, 3e8f, 3e8f, 3e8f);
        plab [blin*SEG + tid] = -3e38f;
    }
    if (tid == 0) { cntP[blin] = (unsigned)padTo; cntN[blin] = (unsigned)tn; }

    // block loss partial
    for (int off = 32; off; off >>= 1) local += __shfl_down(local, off);
    if (lane == 0) red[wid] = local;
    __syncthreads();
    if (tid == 0) partial1[blin] = red[0] + red[1] + red[2] + red[3];
}

// k2: per (iseg, b, isub) block; 8-deep register-batched j loads hide L2
// latency; jq 4-way j-split; fused noobj reduction, 1 atomic per block.
__global__ __launch_bounds__(512) void k2_fused(char* __restrict__ ws,
                                                float* __restrict__ out)
{
    const float*    partial1 = (const float*)(ws + OFF_P1);
    const unsigned* cntP  = (const unsigned*)(ws + OFF_CP);
    const unsigned* cntN  = (const unsigned*)(ws + OFF_CN);
    const float4*   plbox = (const float4*)(ws + OFF_PLB);
    const float*    plab  = (const float*) (ws + OFF_PLA);
    const float4*   nlbox = (const float4*)(ws + OFF_NLB);
    const float*    nlval = (const float*) (ws + OFF_NLV);

    const int tid  = threadIdx.x;
    const int jq   = tid >> 7;          // 0..3 (uniform per wave)
    const int il   = tid & 127;
    const int iseg = blockIdx.x;        // 0..7
    const int b    = blockIdx.y;
    const int isub = blockIdx.z;        // 0..1
    const int blin = b*CHK + iseg;
    const int isl  = isub + 2*il;       // interleaved slot -> balanced halves

    __shared__ float smdr[512];
    __shared__ float red[8];

    const int nn = (int)cntN[blin];
    const bool valid = isl < nn;
    float4 p = nlbox[blin*SEG + isl];   // poison-safe if invalid (discarded)
    float t0 = 0.6f * ((p.z - p.x) * (p.w - p.y) + EPSF);

    float md = -3e38f;
    for (int seg = 0; seg < CHK; seg++) {
        const int pc = (int)cntP[b*CHK + seg];         // multiple of 32
        const float4* jb = plbox + (b*CHK + seg)*SEG;
        const float*  ja = plab  + (b*CHK + seg)*SEG;
        for (int m = 0; m < pc; m += 32) {
            const int j0 = m + jq*8;
            float4 g[8];
            float  a[8];
            #pragma unroll
            for (int t = 0; t < 8; t++) {              // 16 loads in flight
                g[t] = jb[j0 + t];
                a[t] = ja[j0 + t];
            }
            #pragma unroll
            for (int t = 0; t < 8; t++) {
                float ax = fmaxf(p.x, g[t].x), ay = fmaxf(p.y, g[t].y);
                float bx = fminf(p.z, g[t].z), by = fminf(p.w, g[t].w);
                float in0 = fmaxf(bx - ax, 0.f) * fmaxf(by - ay, 0.f);
                md = fmaxf(md, fmaf(1.6f, in0, a[t]));  // 1.6*inter - 0.6*area_b
            }
        }
    }
    smdr[tid] = md;
    __syncthreads();

    float v = 0.f;
    if (tid < 128) {                    // jq=0 threads (same il, same p/t0)
        float m0 = fmaxf(fmaxf(smdr[tid], smdr[tid+128]),
                         fmaxf(smdr[tid+256], smdr[tid+384]));
        // kept (noobj) <=> NOT (iou >= 0.6) <=> m0 < 0.6*(area_a+eps)
        if (valid && m0 < t0) v = nlval[blin*SEG + isl];
        if (tid == 0 && isub == 0) v += partial1[blin];
    }
    for (int off = 32; off; off >>= 1) v += __shfl_down(v, off);
    int wid = tid >> 6, lane = tid & 63;
    if (lane == 0) red[wid] = v;
    __syncthreads();
    if (tid == 0) {
        float s = 0.f;
        #pragma unroll
        for (int w = 0; w < 8; w++) s += red[w];
        atomicAdd(out, s);
    }
}

extern "C" void kernel_launch(void* const* d_in, const int* in_sizes, int n_in,
                              void* d_out, int out_size, void* d_ws, size_t ws_size,
                              hipStream_t stream) {
    const float* pred  = (const float*)d_in[0];
    const float* gt_   = (const float*)d_in[1];
    const float* anch  = (const float*)d_in[2];
    const int*   epoch = (const int*)d_in[3];
    float* out = (float*)d_out;
    char*  ws  = (char*)d_ws;

    dim3 g1(CHK, BS_);
    k1_elemwise<<<g1, 256, 0, stream>>>(pred, gt_, anch, epoch, ws, out);
    dim3 g2(CHK, BS_, 2);
    k2_fused<<<g2, 512, 0, stream>>>(ws, out);
}